// Round 3
// baseline (2544.481 us; speedup 1.0000x reference)
//
#include <hip/hip_runtime.h>

// GatingNet fused: logits = tanh(h @ W1^T + b1) @ W2^T + b2; top-2 masked softmax.
// N=131072, H=1024, E=64, fp32 inputs.
//
// v2 MFMA path: BM=128, 512 threads (8 waves = 2M x 4N), 1 block/CU.
//  - GEMM1 on matrix cores via fp16 2-split / 3-product fp32 emulation:
//      a ~= hi + 2^-11 * lo  (hi = fp16(a) RTE, lo = fp16((a-hi)*2048))
//      a*b ~= ah*bh (acc0) + 2^-11*(ah*bm + am*bh) (acc1); fold in epilogue.
//  - W1 pre-split once into d_ws (4 MB) in exact LDS tile order -> staged with
//    global_load_lds dwordx4, DOUBLE-BUFFERED: stage(kt+1) issued before compute(kt),
//    single barrier per K-step (stage latency hidden under convert+ds_read+MFMA).
//  - h fragments loaded DIRECTLY global->VGPR (2x float4 per row-fragment, L1-served
//    across the 4 N-waves) and split in-register -> no h LDS traffic.
//  - A tile fp32 in LDS [256 cols][131] (133 KB; staging buffers overlap it phase-wise).
//  - GEMM2 + top-2 softmax: two 256-thread halves each running the previously
//    verified 64-row fp32 pattern.
// Fallback to the verified fp32 kernel if ws_size < 4 MB.

constexpr int KT         = 32;
constexpr int AS2        = 131;                   // A tile col-major [c][row], odd stride
constexpr int W2S_STRIDE = 68;                    // W2 tile [c][expert]
constexpr int W2S_OFF2   = 256 * AS2;             // 33536 floats
constexpr int SMEM2_FLOATS = W2S_OFF2 + KT * W2S_STRIDE;  // 35712 floats = 142848 B -> 1 block/CU

// ---- fp32 fallback kernel constants ----
constexpr int A_STRIDE   = 65;
constexpr int F32_W2S_OFF = 256 * A_STRIDE;               // 16640
constexpr int F32_SMEM   = F32_W2S_OFF + KT * W2S_STRIDE; // 18816
constexpr int F32_HS_STRIDE  = 68;
constexpr int F32_WS_STRIDE  = 324;
constexpr int F32_WS_OFF   = KT * F32_HS_STRIDE;

typedef __attribute__((ext_vector_type(8))) _Float16 half8;
typedef __attribute__((ext_vector_type(4))) float f32x4;

__device__ __forceinline__ float fast_tanh(float x) {
  float e = __expf(2.0f * x);
  return 1.0f - 2.0f / (e + 1.0f);
}

__device__ __forceinline__ void gload_lds16(const void* g, void* l) {
  __builtin_amdgcn_global_load_lds(
      (const __attribute__((address_space(1))) unsigned int*)g,
      (__attribute__((address_space(3))) unsigned int*)l, 16, 0, 0);
}

// 8 fp32 -> hi/lo fp16 planes (RTE casts; lo = residual * 2048, normal-range;
// dropped lo*lo term error ~2^-22|ab|).
__device__ __forceinline__ void split8(const float4 a, const float4 b, half8& hi, half8& lo) {
  float v[8] = {a.x, a.y, a.z, a.w, b.x, b.y, b.z, b.w};
#pragma unroll
  for (int i = 0; i < 8; ++i) {
    _Float16 x = (_Float16)v[i];
    hi[i] = x;
    lo[i] = (_Float16)((v[i] - (float)x) * 2048.0f);
  }
}

// ---------------- pre-split kernel: W1 -> ws (fp16 hi/lo planes, LDS tile order) --------------
// ws halfs layout: [kt 32][chunk 4] tiles of 16384 halfs:
//   tile = [plane 2][kb 4][col 256][8 halfs], element (col,k): k = kt*32 + kb*8 + j
__global__ void __launch_bounds__(256)
w1_split(const float* __restrict__ W1, _Float16* __restrict__ ws) {
  const int tid   = blockIdx.x * 256 + threadIdx.x;  // 0..131071
  const int col   = tid & 255;
  const int kb    = (tid >> 8) & 3;
  const int chunk = (tid >> 10) & 3;
  const int kt    = tid >> 12;
  const float* src = W1 + (size_t)(chunk * 256 + col) * 1024 + kt * 32 + kb * 8;
  float4 v0 = *(const float4*)src;
  float4 v1 = *(const float4*)(src + 4);
  float vv[8] = {v0.x, v0.y, v0.z, v0.w, v1.x, v1.y, v1.z, v1.w};
  half8 hi, lo;
#pragma unroll
  for (int j = 0; j < 8; ++j) {
    _Float16 a = (_Float16)vv[j];
    hi[j] = a;
    lo[j] = (_Float16)((vv[j] - (float)a) * 2048.0f);
  }
  _Float16* base = ws + (size_t)(kt * 4 + chunk) * 16384;
  *(half8*)(base + kb * 2048 + col * 8)        = hi;
  *(half8*)(base + 8192 + kb * 2048 + col * 8) = lo;
}

// ---------------- main MFMA kernel v2: BM=128, 512 threads ----------------
__global__ void __launch_bounds__(512, 2)
gating_mfma2(const float* __restrict__ h, const _Float16* __restrict__ wsp,
             const float* __restrict__ b1, const float* __restrict__ W2,
             const float* __restrict__ b2, float* __restrict__ out) {
  __shared__ float smem[SMEM2_FLOATS];
  char* smb   = (char*)smem;
  float* Al   = smem;               // col-major [cloc][AS2], 133 KB
  float* w2s  = smem + W2S_OFF2;

  const int t    = threadIdx.x;
  const int lane = t & 63;
  const int wave = t >> 6;          // 0..7
  const int wm   = wave >> 2;       // M-half (64 rows)
  const int wn   = wave & 3;        // col quarter (64 cols of the 256-chunk)
  const int l15  = lane & 15;
  const int l4   = lane >> 4;       // 0..3 = k-slot
  const long rowbase = (long)blockIdx.x * 128;

  // per-lane h row pointers (fragment = 8 consecutive k of one row)
  const float* hp[4];
#pragma unroll
  for (int mt = 0; mt < 4; ++mt)
    hp[mt] = h + (rowbase + wm * 64 + mt * 16 + l15) * 1024 + l4 * 8;

  // GEMM2 / softmax ids: two 256-thread halves, each = verified 64-row pattern
  const int g   = t >> 8;           // row half 0/1
  const int u   = t & 255;
  const int tx  = u & 15;           // 4-row group
  const int ty2 = u >> 4;           // 4-expert group

  float b2v[4];
#pragma unroll
  for (int l = 0; l < 4; ++l) b2v[l] = b2[ty2 * 4 + l];

  float lacc[4][4];
#pragma unroll
  for (int j = 0; j < 4; ++j)
#pragma unroll
    for (int l = 0; l < 4; ++l) lacc[j][l] = 0.0f;

  for (int chunk = 0; chunk < 4; ++chunk) {
    const int cbase = chunk * 256;

    float b1v[4];
#pragma unroll
    for (int nt = 0; nt < 4; ++nt) b1v[nt] = b1[cbase + wn * 64 + nt * 16 + l15];

    f32x4 acc0[4][4], acc1[4][4];
    {
      f32x4 z = {0.0f, 0.0f, 0.0f, 0.0f};
#pragma unroll
      for (int mt = 0; mt < 4; ++mt)
#pragma unroll
        for (int nt = 0; nt < 4; ++nt) { acc0[mt][nt] = z; acc1[mt][nt] = z; }
    }

    // stage W1 tile kt -> buf (32 KB linear, pre-arranged layout [plane][kb][col][8])
    auto stage = [&](int kt, int buf) {
      const char* srcW = (const char*)wsp + (((size_t)kt * 4 + chunk) << 15);
      char* dst = smb + buf * 32768;
      const int o0 = t * 16;
#pragma unroll
      for (int i = 0; i < 4; ++i)
        gload_lds16(srcW + o0 + i * 8192, dst + o0 + i * 8192);
    };

    __syncthreads();            // protect buf region (prev phase readers done)
    stage(0, 0);
    __syncthreads();            // drain prologue stage

    // ---- GEMM1 K-loop: 2-phase double-buffered pipeline, one barrier per kt ----
    for (int kt = 0; kt < 32; ++kt) {
      // h fragment loads (global, L1-shared across N-waves)
      float4 hr0[4], hr1[4];
#pragma unroll
      for (int mt = 0; mt < 4; ++mt) {
        const float* p = hp[mt] + kt * 32;
        hr0[mt] = *(const float4*)p;
        hr1[mt] = *(const float4*)(p + 4);
      }
      // issue next-tile staging early; drained by this iteration's ending barrier
      if (kt < 31) stage(kt + 1, (kt + 1) & 1);

      half8 ah[4], am[4];
#pragma unroll
      for (int mt = 0; mt < 4; ++mt) split8(hr0[mt], hr1[mt], ah[mt], am[mt]);

      const char* bufp = smb + (kt & 1) * 32768 + l4 * 4096;
#pragma unroll
      for (int nt = 0; nt < 4; ++nt) {
        const char* bp = bufp + (wn * 64 + nt * 16 + l15) * 16;
        half8 bh = *(const half8*)bp;
        half8 bm = *(const half8*)(bp + 16384);
#pragma unroll
        for (int mt = 0; mt < 4; ++mt) {
          acc0[mt][nt] = __builtin_amdgcn_mfma_f32_16x16x32_f16(ah[mt], bh, acc0[mt][nt], 0, 0, 0);
          acc1[mt][nt] = __builtin_amdgcn_mfma_f32_16x16x32_f16(ah[mt], bm, acc1[mt][nt], 0, 0, 0);
          acc1[mt][nt] = __builtin_amdgcn_mfma_f32_16x16x32_f16(am[mt], bh, acc1[mt][nt], 0, 0, 0);
        }
      }
      __syncthreads();          // drains stage(kt+1) + this iter's LDS reads
    }

    // ---- epilogue: fold, +b1, tanh -> A tile (col-major [c][row], overwrites bufs) ----
#pragma unroll
    for (int nt = 0; nt < 4; ++nt) {
      const int cloc = wn * 64 + nt * 16 + l15;
#pragma unroll
      for (int mt = 0; mt < 4; ++mt) {
        const int r0 = wm * 64 + mt * 16 + l4 * 4;
#pragma unroll
        for (int r = 0; r < 4; ++r) {
          float pre = acc0[mt][nt][r] + acc1[mt][nt][r] * (1.0f / 2048.0f) + b1v[nt];
          Al[cloc * AS2 + r0 + r] = fast_tanh(pre);
        }
      }
    }

    // ---- GEMM2 partial: logits[128 x 64] += A_chunk[128 x 256] * W2[.,chunk]^T ----
    for (int c2 = 0; c2 < 256; c2 += KT) {
      __syncthreads();          // also covers epilogue A-writes on first iter
      {
        const int e  = t >> 3;          // 0..63
        const int cq = (t & 7) * 4;     // 0..28
        float4 v = *(const float4*)(W2 + (long)e * 1024 + cbase + c2 + cq);
        w2s[(cq + 0) * W2S_STRIDE + e] = v.x;
        w2s[(cq + 1) * W2S_STRIDE + e] = v.y;
        w2s[(cq + 2) * W2S_STRIDE + e] = v.z;
        w2s[(cq + 3) * W2S_STRIDE + e] = v.w;
      }
      __syncthreads();
#pragma unroll
      for (int c = 0; c < KT; ++c) {
        const int cloc = c2 + c;
        const float* ap = Al + cloc * AS2 + g * 64 + tx * 4;
        const float a0 = ap[0], a1 = ap[1], a2 = ap[2], a3 = ap[3];
        const float4 wv = *(const float4*)(w2s + c * W2S_STRIDE + ty2 * 4);
        lacc[0][0] += a0 * wv.x; lacc[0][1] += a0 * wv.y; lacc[0][2] += a0 * wv.z; lacc[0][3] += a0 * wv.w;
        lacc[1][0] += a1 * wv.x; lacc[1][1] += a1 * wv.y; lacc[1][2] += a1 * wv.z; lacc[1][3] += a1 * wv.w;
        lacc[2][0] += a2 * wv.x; lacc[2][1] += a2 * wv.y; lacc[2][2] += a2 * wv.z; lacc[2][3] += a2 * wv.w;
        lacc[3][0] += a3 * wv.x; lacc[3][1] += a3 * wv.y; lacc[3][2] += a3 * wv.z; lacc[3][3] += a3 * wv.w;
      }
    }
  }

  // ---- logits -> LDS, then per-row top-2 masked softmax (two 64-row halves) ----
  __syncthreads();
#pragma unroll
  for (int j = 0; j < 4; ++j)
#pragma unroll
    for (int l = 0; l < 4; ++l)
      smem[(g * 64 + tx * 4 + j) * 68 + ty2 * 4 + l] = lacc[j][l] + b2v[l];
  __syncthreads();

  {
    const int row = g * 64 + (u >> 2);  // 0..127
    const int sub = u & 3;              // quarter of 64 experts
    float v1 = -1e30f, v2 = -1e30f;
    int i1 = -1, i2 = -1;
#pragma unroll
    for (int j = 0; j < 16; ++j) {
      const float v = smem[row * 68 + sub * 16 + j];
      const int idx = sub * 16 + j;
      if (v > v1) { v2 = v1; i2 = i1; v1 = v; i1 = idx; }
      else if (v > v2) { v2 = v; i2 = idx; }
    }
#pragma unroll
    for (int off = 1; off <= 2; off <<= 1) {
      const float ov1 = __shfl_xor(v1, off);
      const int   oi1 = __shfl_xor(i1, off);
      const float ov2 = __shfl_xor(v2, off);
      const int   oi2 = __shfl_xor(i2, off);
      if (ov1 > v1) {
        if (v1 > ov2) { v2 = v1; i2 = i1; }
        else          { v2 = ov2; i2 = oi2; }
        v1 = ov1; i1 = oi1;
      } else if (ov1 > v2) {
        v2 = ov1; i2 = oi1;
      }
    }
    const float e2 = __expf(v2 - v1);
    const float inv = 1.0f / (1.0f + e2);
    const float p1 = inv, p2 = e2 * inv;
    float* orow = out + (rowbase + row) * 64 + sub * 16;
#pragma unroll
    for (int q = 0; q < 4; ++q) {
      const int idx0 = sub * 16 + q * 4;
      float4 o;
      o.x = (idx0 + 0 == i1) ? p1 : ((idx0 + 0 == i2) ? p2 : 0.0f);
      o.y = (idx0 + 1 == i1) ? p1 : ((idx0 + 1 == i2) ? p2 : 0.0f);
      o.z = (idx0 + 2 == i1) ? p1 : ((idx0 + 2 == i2) ? p2 : 0.0f);
      o.w = (idx0 + 3 == i1) ? p1 : ((idx0 + 3 == i2) ? p2 : 0.0f);
      *(float4*)(orow + q * 4) = o;
    }
  }
}

// ---------------- fp32 fallback (verified kernel, unchanged) ----------------
__global__ void __launch_bounds__(256, 2)
gating_fused(const float* __restrict__ h, const float* __restrict__ W1,
             const float* __restrict__ b1, const float* __restrict__ W2,
             const float* __restrict__ b2, float* __restrict__ out) {
  __shared__ float smem[F32_SMEM];
  float* hs  = smem;
  float* ws  = smem + F32_WS_OFF;
  float* Al  = smem;
  float* w2s = smem + F32_W2S_OFF;

  const int t  = threadIdx.x;
  const int tx = t & 15;
  const int ty = t >> 4;
  const long rowbase = (long)blockIdx.x * 64;

  float b2v[4];
#pragma unroll
  for (int l = 0; l < 4; ++l) b2v[l] = b2[ty * 4 + l];

  float lacc[4][4];
#pragma unroll
  for (int j = 0; j < 4; ++j)
#pragma unroll
    for (int l = 0; l < 4; ++l) lacc[j][l] = 0.0f;

  for (int chunk = 0; chunk < 4; ++chunk) {
    const int cbase = chunk * 256;

    float b1v[16];
#pragma unroll
    for (int q = 0; q < 4; ++q) {
      float4 v = *(const float4*)(b1 + cbase + tx * 16 + q * 4);
      b1v[q * 4 + 0] = v.x; b1v[q * 4 + 1] = v.y;
      b1v[q * 4 + 2] = v.z; b1v[q * 4 + 3] = v.w;
    }

    float acc[16][4];
#pragma unroll
    for (int c = 0; c < 16; ++c)
#pragma unroll
      for (int j = 0; j < 4; ++j) acc[c][j] = 0.0f;

    for (int kt = 0; kt < 1024 / KT; ++kt) {
      const int kk = kt * KT;
      __syncthreads();
      {
        const int kq = (t & 7) * 4;
        const int rr = t >> 3;
#pragma unroll
        for (int p = 0; p < 2; ++p) {
          const int r = p * 32 + rr;
          float4 v = *(const float4*)(h + (rowbase + r) * 1024 + kk + kq);
          hs[(kq + 0) * F32_HS_STRIDE + r] = v.x;
          hs[(kq + 1) * F32_HS_STRIDE + r] = v.y;
          hs[(kq + 2) * F32_HS_STRIDE + r] = v.z;
          hs[(kq + 3) * F32_HS_STRIDE + r] = v.w;
        }
#pragma unroll
        for (int p = 0; p < 8; ++p) {
          const int ol = p * 32 + rr;
          float4 v = *(const float4*)(W1 + (long)(cbase + ol) * 1024 + kk + kq);
          float* dst = ws + (ol >> 4) * 20 + (ol & 15);
          dst[(kq + 0) * F32_WS_STRIDE] = v.x;
          dst[(kq + 1) * F32_WS_STRIDE] = v.y;
          dst[(kq + 2) * F32_WS_STRIDE] = v.z;
          dst[(kq + 3) * F32_WS_STRIDE] = v.w;
        }
      }
      __syncthreads();
#pragma unroll
      for (int k = 0; k < KT; ++k) {
        float4 a = *(const float4*)(hs + k * F32_HS_STRIDE + ty * 4);
        const float* wr = ws + k * F32_WS_STRIDE + tx * 20;
        float4 w0 = *(const float4*)(wr + 0);
        float4 w1 = *(const float4*)(wr + 4);
        float4 w2q = *(const float4*)(wr + 8);
        float4 w3 = *(const float4*)(wr + 12);
        float wv[16] = {w0.x, w0.y, w0.z, w0.w, w1.x, w1.y, w1.z, w1.w,
                        w2q.x, w2q.y, w2q.z, w2q.w, w3.x, w3.y, w3.z, w3.w};
#pragma unroll
        for (int c = 0; c < 16; ++c) {
          acc[c][0] += a.x * wv[c];
          acc[c][1] += a.y * wv[c];
          acc[c][2] += a.z * wv[c];
          acc[c][3] += a.w * wv[c];
        }
      }
    }

    __syncthreads();
#pragma unroll
    for (int c = 0; c < 16; ++c) {
      const int cloc = tx * 16 + c;
#pragma unroll
      for (int j = 0; j < 4; ++j)
        Al[cloc * A_STRIDE + ty * 4 + j] = fast_tanh(acc[c][j] + b1v[c]);
    }

    for (int c2 = 0; c2 < 256; c2 += KT) {
      __syncthreads();
      {
        const int e = t >> 2;
        const int cq = (t & 3) * 8;
#pragma unroll
        for (int p = 0; p < 2; ++p) {
          float4 v = *(const float4*)(W2 + (long)e * 1024 + cbase + c2 + cq + p * 4);
          w2s[(cq + p * 4 + 0) * W2S_STRIDE + e] = v.x;
          w2s[(cq + p * 4 + 1) * W2S_STRIDE + e] = v.y;
          w2s[(cq + p * 4 + 2) * W2S_STRIDE + e] = v.z;
          w2s[(cq + p * 4 + 3) * W2S_STRIDE + e] = v.w;
        }
      }
      __syncthreads();
#pragma unroll
      for (int c = 0; c < KT; ++c) {
        const int cloc = c2 + c;
        const float* ap = Al + cloc * A_STRIDE + tx * 4;
        const float a0 = ap[0], a1 = ap[1], a2 = ap[2], a3 = ap[3];
        const float4 wv = *(const float4*)(w2s + c * W2S_STRIDE + ty * 4);
        lacc[0][0] += a0 * wv.x; lacc[0][1] += a0 * wv.y; lacc[0][2] += a0 * wv.z; lacc[0][3] += a0 * wv.w;
        lacc[1][0] += a1 * wv.x; lacc[1][1] += a1 * wv.y; lacc[1][2] += a1 * wv.z; lacc[1][3] += a1 * wv.w;
        lacc[2][0] += a2 * wv.x; lacc[2][1] += a2 * wv.y; lacc[2][2] += a2 * wv.z; lacc[2][3] += a2 * wv.w;
        lacc[3][0] += a3 * wv.x; lacc[3][1] += a3 * wv.y; lacc[3][2] += a3 * wv.z; lacc[3][3] += a3 * wv.w;
      }
    }
  }

  __syncthreads();
#pragma unroll
  for (int j = 0; j < 4; ++j)
#pragma unroll
    for (int l = 0; l < 4; ++l)
      smem[(tx * 4 + j) * 68 + ty * 4 + l] = lacc[j][l] + b2v[l];
  __syncthreads();

  {
    const int row = t >> 2;
    const int sub = t & 3;
    float v1 = -1e30f, v2 = -1e30f;
    int i1 = -1, i2 = -1;
#pragma unroll
    for (int j = 0; j < 16; ++j) {
      const float v = smem[row * 68 + sub * 16 + j];
      const int idx = sub * 16 + j;
      if (v > v1) { v2 = v1; i2 = i1; v1 = v; i1 = idx; }
      else if (v > v2) { v2 = v; i2 = idx; }
    }
#pragma unroll
    for (int off = 1; off <= 2; off <<= 1) {
      const float ov1 = __shfl_xor(v1, off);
      const int   oi1 = __shfl_xor(i1, off);
      const float ov2 = __shfl_xor(v2, off);
      const int   oi2 = __shfl_xor(i2, off);
      if (ov1 > v1) {
        if (v1 > ov2) { v2 = v1; i2 = i1; }
        else          { v2 = ov2; i2 = oi2; }
        v1 = ov1; i1 = oi1;
      } else if (ov1 > v2) {
        v2 = ov1; i2 = oi1;
      }
    }
    const float e2 = __expf(v2 - v1);
    const float inv = 1.0f / (1.0f + e2);
    const float p1 = inv, p2 = e2 * inv;
    float* orow = out + (rowbase + row) * 64 + sub * 16;
#pragma unroll
    for (int q = 0; q < 4; ++q) {
      const int idx0 = sub * 16 + q * 4;
      float4 o;
      o.x = (idx0 + 0 == i1) ? p1 : ((idx0 + 0 == i2) ? p2 : 0.0f);
      o.y = (idx0 + 1 == i1) ? p1 : ((idx0 + 1 == i2) ? p2 : 0.0f);
      o.z = (idx0 + 2 == i1) ? p1 : ((idx0 + 2 == i2) ? p2 : 0.0f);
      o.w = (idx0 + 3 == i1) ? p1 : ((idx0 + 3 == i2) ? p2 : 0.0f);
      *(float4*)(orow + q * 4) = o;
    }
  }
}

extern "C" void kernel_launch(void* const* d_in, const int* in_sizes, int n_in,
                              void* d_out, int out_size, void* d_ws, size_t ws_size,
                              hipStream_t stream) {
  const float* h  = (const float*)d_in[0];
  const float* W1 = (const float*)d_in[1];
  const float* b1 = (const float*)d_in[2];
  const float* W2 = (const float*)d_in[3];
  const float* b2 = (const float*)d_in[4];
  float* out = (float*)d_out;
  // epoch=5 >= warmup=0 and top_k=2 -> top-2 masked softmax path (inputs fixed by harness)
  if (d_ws && ws_size >= (size_t)4 * 1024 * 1024) {
    _Float16* wsp = (_Float16*)d_ws;
    w1_split<<<dim3(512), dim3(256), 0, stream>>>(W1, wsp);
    gating_mfma2<<<dim3(131072 / 128), dim3(512), 0, stream>>>(h, wsp, b1, W2, b2, out);
  } else {
    gating_fused<<<dim3(131072 / 64), dim3(256), 0, stream>>>(h, W1, b1, W2, b2, out);
  }
}

// Round 4
// 1747.966 us; speedup vs baseline: 1.4557x; 1.4557x over previous
//
#include <hip/hip_runtime.h>

// GatingNet fused: logits = tanh(h @ W1^T + b1) @ W2^T + b2; top-2 masked softmax.
// N=131072, H=1024, E=64, fp32 inputs.
//
// v3 MFMA path: BM=128, 512 threads (8 waves = 2M x 4N), 1 block/CU.
//  - GEMM1 on matrix cores via fp16 2-split / 3-product fp32 emulation:
//      a ~= hi + 2^-11 * lo  (hi = fp16(a) RTE, lo = fp16((a-hi)*2048))
//      a*b ~= ah*bh (acc0) + 2^-11*(ah*bm + am*bh) (acc1); fold in epilogue.
//  - W1 pre-split once into d_ws (4 MB) in exact LDS tile order -> staged with
//    global_load_lds dwordx4, double-buffered, issued before compute(kt).
//  - h staged COOPERATIVELY through LDS (v2's per-lane global gather was the
//    regression: 16 rows x 4 scattered 16B per wave-load ~= 8x L1 over-traffic).
//    Thread t loads 32B contiguous of row t>>2 (full line util), converts to
//    hi/lo fp16 in-register, ds_writes into a double-buffered h tile. Loads
//    issued at top of iteration kt for kt+1; convert+write after the MFMAs so
//    global latency hides under compute. Single barrier per kt.
//  - A tile fp32 in LDS [256 cols][131] (134 KB; staging 96 KB overlaps it).
//  - GEMM2 + top-2 softmax: two 256-thread halves of the verified fp32 pattern.
// Fallback to the verified fp32 kernel if ws_size < 4 MB.

constexpr int KT         = 32;
constexpr int AS2        = 131;                   // A tile col-major [c][row], odd stride
constexpr int W2S_STRIDE = 68;                    // W2 tile [c][expert]
constexpr int W2S_OFF2   = 256 * AS2;             // 33536 floats
constexpr int SMEM2_FLOATS = W2S_OFF2 + KT * W2S_STRIDE;  // 35712 floats = 142848 B -> 1 block/CU

// staging byte offsets (overlap the A-tile region, phase-alternated)
constexpr int WS2_B = 0;          // W1 dbuf: 2 x 32768 B   [buf][plane][kb4][col256][16B]
constexpr int HS2_B = 65536;      // h  dbuf: 2 x 16384 B   [buf][plane][kb4][row128][16B]

// ---- fp32 fallback kernel constants ----
constexpr int A_STRIDE   = 65;
constexpr int F32_W2S_OFF = 256 * A_STRIDE;               // 16640
constexpr int F32_SMEM   = F32_W2S_OFF + KT * W2S_STRIDE; // 18816
constexpr int F32_HS_STRIDE  = 68;
constexpr int F32_WS_STRIDE  = 324;
constexpr int F32_WS_OFF   = KT * F32_HS_STRIDE;

typedef __attribute__((ext_vector_type(8))) _Float16 half8;
typedef __attribute__((ext_vector_type(4))) float f32x4;

__device__ __forceinline__ float fast_tanh(float x) {
  float e = __expf(2.0f * x);
  return 1.0f - 2.0f / (e + 1.0f);
}

__device__ __forceinline__ void gload_lds16(const void* g, void* l) {
  __builtin_amdgcn_global_load_lds(
      (const __attribute__((address_space(1))) unsigned int*)g,
      (__attribute__((address_space(3))) unsigned int*)l, 16, 0, 0);
}

// 8 fp32 -> hi/lo fp16 planes (RTE casts; lo = residual * 2048, normal-range;
// dropped lo*lo term error ~2^-22|ab|).
__device__ __forceinline__ void split8(const float4 a, const float4 b, half8& hi, half8& lo) {
  float v[8] = {a.x, a.y, a.z, a.w, b.x, b.y, b.z, b.w};
#pragma unroll
  for (int i = 0; i < 8; ++i) {
    _Float16 x = (_Float16)v[i];
    hi[i] = x;
    lo[i] = (_Float16)((v[i] - (float)x) * 2048.0f);
  }
}

// ---------------- pre-split kernel: W1 -> ws (fp16 hi/lo planes, LDS tile order) --------------
// ws halfs layout: [kt 32][chunk 4] tiles of 16384 halfs:
//   tile = [plane 2][kb 4][col 256][8 halfs], element (col,k): k = kt*32 + kb*8 + j
__global__ void __launch_bounds__(256)
w1_split(const float* __restrict__ W1, _Float16* __restrict__ ws) {
  const int tid   = blockIdx.x * 256 + threadIdx.x;  // 0..131071
  const int col   = tid & 255;
  const int kb    = (tid >> 8) & 3;
  const int chunk = (tid >> 10) & 3;
  const int kt    = tid >> 12;
  const float* src = W1 + (size_t)(chunk * 256 + col) * 1024 + kt * 32 + kb * 8;
  float4 v0 = *(const float4*)src;
  float4 v1 = *(const float4*)(src + 4);
  float vv[8] = {v0.x, v0.y, v0.z, v0.w, v1.x, v1.y, v1.z, v1.w};
  half8 hi, lo;
#pragma unroll
  for (int j = 0; j < 8; ++j) {
    _Float16 a = (_Float16)vv[j];
    hi[j] = a;
    lo[j] = (_Float16)((vv[j] - (float)a) * 2048.0f);
  }
  _Float16* base = ws + (size_t)(kt * 4 + chunk) * 16384;
  *(half8*)(base + kb * 2048 + col * 8)        = hi;
  *(half8*)(base + 8192 + kb * 2048 + col * 8) = lo;
}

// ---------------- main MFMA kernel v3: BM=128, 512 threads, h via LDS ----------------
__global__ void __launch_bounds__(512, 2)
gating_mfma3(const float* __restrict__ h, const _Float16* __restrict__ wsp,
             const float* __restrict__ b1, const float* __restrict__ W2,
             const float* __restrict__ b2, float* __restrict__ out) {
  __shared__ float smem[SMEM2_FLOATS];
  char* smb   = (char*)smem;
  float* Al   = smem;               // col-major [cloc][AS2], 134 KB
  float* w2s  = smem + W2S_OFF2;

  const int t    = threadIdx.x;
  const int lane = t & 63;
  const int wave = t >> 6;          // 0..7
  const int wm   = wave >> 2;       // M-half (64 rows)
  const int wn   = wave & 3;        // col quarter (64 cols of the 256-chunk)
  const int l15  = lane & 15;
  const int l4   = lane >> 4;       // 0..3 = k-slot
  const long rowbase = (long)blockIdx.x * 128;

  // h staging ids: thread t loads 32B contiguous of row t>>2 (coalesced)
  const int srow = t >> 2;          // 0..127
  const int skb  = t & 3;           // 0..3
  const float* hrow = h + (rowbase + srow) * 1024 + skb * 8;

  // GEMM2 / softmax ids: two 256-thread halves, each = verified 64-row pattern
  const int g   = t >> 8;           // row half 0/1
  const int u   = t & 255;
  const int tx  = u & 15;           // 4-row group
  const int ty2 = u >> 4;           // 4-expert group

  float b2v[4];
#pragma unroll
  for (int l = 0; l < 4; ++l) b2v[l] = b2[ty2 * 4 + l];

  float lacc[4][4];
#pragma unroll
  for (int j = 0; j < 4; ++j)
#pragma unroll
    for (int l = 0; l < 4; ++l) lacc[j][l] = 0.0f;

  for (int chunk = 0; chunk < 4; ++chunk) {
    const int cbase = chunk * 256;

    float b1v[4];
#pragma unroll
    for (int nt = 0; nt < 4; ++nt) b1v[nt] = b1[cbase + wn * 64 + nt * 16 + l15];

    f32x4 acc0[4][4], acc1[4][4];
    {
      f32x4 z = {0.0f, 0.0f, 0.0f, 0.0f};
#pragma unroll
      for (int mt = 0; mt < 4; ++mt)
#pragma unroll
        for (int nt = 0; nt < 4; ++nt) { acc0[mt][nt] = z; acc1[mt][nt] = z; }
    }

    // stage W1 tile kt -> wbuf (32 KB linear, pre-arranged [plane][kb][col][16B])
    auto stage_w = [&](int kt, int buf) {
      const char* srcW = (const char*)wsp + (((size_t)kt * 4 + chunk) << 15);
      char* dst = smb + WS2_B + buf * 32768;
      const int o0 = t * 16;
#pragma unroll
      for (int i = 0; i < 4; ++i)
        gload_lds16(srcW + o0 + i * 8192, dst + o0 + i * 8192);
    };
    // convert + ds_write h regs -> hbuf
    auto write_h = [&](const float4 a, const float4 b, int buf) {
      half8 hi, lo;
      split8(a, b, hi, lo);
      char* hb = smb + HS2_B + buf * 16384 + skb * 2048 + srow * 16;
      *(half8*)hb          = hi;   // plane 0
      *(half8*)(hb + 8192) = lo;   // plane 1
    };

    __syncthreads();            // prev-chunk GEMM2 readers done with A region
    {                           // prologue: stage kt=0 (h + W1), then drain
      float4 a0 = *(const float4*)hrow;
      float4 a1 = *(const float4*)(hrow + 4);
      stage_w(0, 0);
      write_h(a0, a1, 0);
    }
    __syncthreads();            // drains gload_lds (vmcnt) + ds_writes (lgkm)

    // ---- GEMM1 K-loop: double-buffered, single barrier per kt ----
    for (int kt = 0; kt < 32; ++kt) {
      const int cur = kt & 1, nxt = cur ^ 1;

      // issue next-tile staging loads first (latency hides under MFMA below)
      float4 n0, n1;
      if (kt < 31) {
        const float* p = hrow + (kt + 1) * 32;
        n0 = *(const float4*)p;
        n1 = *(const float4*)(p + 4);
        stage_w(kt + 1, nxt);
      }

      // fragments from current buffers
      half8 ah[4], am[4];
      const char* hbp = smb + HS2_B + cur * 16384 + l4 * 2048;
#pragma unroll
      for (int mt = 0; mt < 4; ++mt) {
        const int o = (wm * 64 + mt * 16 + l15) * 16;
        ah[mt] = *(const half8*)(hbp + o);
        am[mt] = *(const half8*)(hbp + 8192 + o);
      }
      const char* bufp = smb + WS2_B + cur * 32768 + l4 * 4096;
#pragma unroll
      for (int nt = 0; nt < 4; ++nt) {
        const char* bp = bufp + (wn * 64 + nt * 16 + l15) * 16;
        half8 bh = *(const half8*)bp;
        half8 bm = *(const half8*)(bp + 16384);
#pragma unroll
        for (int mt = 0; mt < 4; ++mt) {
          acc0[mt][nt] = __builtin_amdgcn_mfma_f32_16x16x32_f16(ah[mt], bh, acc0[mt][nt], 0, 0, 0);
          acc1[mt][nt] = __builtin_amdgcn_mfma_f32_16x16x32_f16(ah[mt], bm, acc1[mt][nt], 0, 0, 0);
          acc1[mt][nt] = __builtin_amdgcn_mfma_f32_16x16x32_f16(am[mt], bh, acc1[mt][nt], 0, 0, 0);
        }
      }

      // convert + write h(kt+1) after the MFMAs (vmcnt wait lands here, hidden)
      if (kt < 31) write_h(n0, n1, nxt);

      __syncthreads();          // drains stage(kt+1) + this iter's LDS reads
    }

    // ---- epilogue: fold, +b1, tanh -> A tile (col-major [c][row], overwrites bufs) ----
#pragma unroll
    for (int nt = 0; nt < 4; ++nt) {
      const int cloc = wn * 64 + nt * 16 + l15;
#pragma unroll
      for (int mt = 0; mt < 4; ++mt) {
        const int r0 = wm * 64 + mt * 16 + l4 * 4;
#pragma unroll
        for (int r = 0; r < 4; ++r) {
          float pre = acc0[mt][nt][r] + acc1[mt][nt][r] * (1.0f / 2048.0f) + b1v[nt];
          Al[cloc * AS2 + r0 + r] = fast_tanh(pre);
        }
      }
    }

    // ---- GEMM2 partial: logits[128 x 64] += A_chunk[128 x 256] * W2[.,chunk]^T ----
    for (int c2 = 0; c2 < 256; c2 += KT) {
      __syncthreads();          // also covers epilogue A-writes on first iter
      {
        const int e  = t >> 3;          // 0..63
        const int cq = (t & 7) * 4;     // 0..28
        float4 v = *(const float4*)(W2 + (long)e * 1024 + cbase + c2 + cq);
        w2s[(cq + 0) * W2S_STRIDE + e] = v.x;
        w2s[(cq + 1) * W2S_STRIDE + e] = v.y;
        w2s[(cq + 2) * W2S_STRIDE + e] = v.z;
        w2s[(cq + 3) * W2S_STRIDE + e] = v.w;
      }
      __syncthreads();
#pragma unroll
      for (int c = 0; c < KT; ++c) {
        const int cloc = c2 + c;
        const float* ap = Al + cloc * AS2 + g * 64 + tx * 4;
        const float a0 = ap[0], a1 = ap[1], a2 = ap[2], a3 = ap[3];
        const float4 wv = *(const float4*)(w2s + c * W2S_STRIDE + ty2 * 4);
        lacc[0][0] += a0 * wv.x; lacc[0][1] += a0 * wv.y; lacc[0][2] += a0 * wv.z; lacc[0][3] += a0 * wv.w;
        lacc[1][0] += a1 * wv.x; lacc[1][1] += a1 * wv.y; lacc[1][2] += a1 * wv.z; lacc[1][3] += a1 * wv.w;
        lacc[2][0] += a2 * wv.x; lacc[2][1] += a2 * wv.y; lacc[2][2] += a2 * wv.z; lacc[2][3] += a2 * wv.w;
        lacc[3][0] += a3 * wv.x; lacc[3][1] += a3 * wv.y; lacc[3][2] += a3 * wv.z; lacc[3][3] += a3 * wv.w;
      }
    }
  }

  // ---- logits -> LDS, then per-row top-2 masked softmax (two 64-row halves) ----
  __syncthreads();
#pragma unroll
  for (int j = 0; j < 4; ++j)
#pragma unroll
    for (int l = 0; l < 4; ++l)
      smem[(g * 64 + tx * 4 + j) * 68 + ty2 * 4 + l] = lacc[j][l] + b2v[l];
  __syncthreads();

  {
    const int row = g * 64 + (u >> 2);  // 0..127
    const int sub = u & 3;              // quarter of 64 experts
    float v1 = -1e30f, v2 = -1e30f;
    int i1 = -1, i2 = -1;
#pragma unroll
    for (int j = 0; j < 16; ++j) {
      const float v = smem[row * 68 + sub * 16 + j];
      const int idx = sub * 16 + j;
      if (v > v1) { v2 = v1; i2 = i1; v1 = v; i1 = idx; }
      else if (v > v2) { v2 = v; i2 = idx; }
    }
#pragma unroll
    for (int off = 1; off <= 2; off <<= 1) {
      const float ov1 = __shfl_xor(v1, off);
      const int   oi1 = __shfl_xor(i1, off);
      const float ov2 = __shfl_xor(v2, off);
      const int   oi2 = __shfl_xor(i2, off);
      if (ov1 > v1) {
        if (v1 > ov2) { v2 = v1; i2 = i1; }
        else          { v2 = ov2; i2 = oi2; }
        v1 = ov1; i1 = oi1;
      } else if (ov1 > v2) {
        v2 = ov1; i2 = oi1;
      }
    }
    const float e2 = __expf(v2 - v1);
    const float inv = 1.0f / (1.0f + e2);
    const float p1 = inv, p2 = e2 * inv;
    float* orow = out + (rowbase + row) * 64 + sub * 16;
#pragma unroll
    for (int q = 0; q < 4; ++q) {
      const int idx0 = sub * 16 + q * 4;
      float4 o;
      o.x = (idx0 + 0 == i1) ? p1 : ((idx0 + 0 == i2) ? p2 : 0.0f);
      o.y = (idx0 + 1 == i1) ? p1 : ((idx0 + 1 == i2) ? p2 : 0.0f);
      o.z = (idx0 + 2 == i1) ? p1 : ((idx0 + 2 == i2) ? p2 : 0.0f);
      o.w = (idx0 + 3 == i1) ? p1 : ((idx0 + 3 == i2) ? p2 : 0.0f);
      *(float4*)(orow + q * 4) = o;
    }
  }
}

// ---------------- fp32 fallback (verified kernel, unchanged) ----------------
__global__ void __launch_bounds__(256, 2)
gating_fused(const float* __restrict__ h, const float* __restrict__ W1,
             const float* __restrict__ b1, const float* __restrict__ W2,
             const float* __restrict__ b2, float* __restrict__ out) {
  __shared__ float smem[F32_SMEM];
  float* hs  = smem;
  float* ws  = smem + F32_WS_OFF;
  float* Al  = smem;
  float* w2s = smem + F32_W2S_OFF;

  const int t  = threadIdx.x;
  const int tx = t & 15;
  const int ty = t >> 4;
  const long rowbase = (long)blockIdx.x * 64;

  float b2v[4];
#pragma unroll
  for (int l = 0; l < 4; ++l) b2v[l] = b2[ty * 4 + l];

  float lacc[4][4];
#pragma unroll
  for (int j = 0; j < 4; ++j)
#pragma unroll
    for (int l = 0; l < 4; ++l) lacc[j][l] = 0.0f;

  for (int chunk = 0; chunk < 4; ++chunk) {
    const int cbase = chunk * 256;

    float b1v[16];
#pragma unroll
    for (int q = 0; q < 4; ++q) {
      float4 v = *(const float4*)(b1 + cbase + tx * 16 + q * 4);
      b1v[q * 4 + 0] = v.x; b1v[q * 4 + 1] = v.y;
      b1v[q * 4 + 2] = v.z; b1v[q * 4 + 3] = v.w;
    }

    float acc[16][4];
#pragma unroll
    for (int c = 0; c < 16; ++c)
#pragma unroll
      for (int j = 0; j < 4; ++j) acc[c][j] = 0.0f;

    for (int kt = 0; kt < 1024 / KT; ++kt) {
      const int kk = kt * KT;
      __syncthreads();
      {
        const int kq = (t & 7) * 4;
        const int rr = t >> 3;
#pragma unroll
        for (int p = 0; p < 2; ++p) {
          const int r = p * 32 + rr;
          float4 v = *(const float4*)(h + (rowbase + r) * 1024 + kk + kq);
          hs[(kq + 0) * F32_HS_STRIDE + r] = v.x;
          hs[(kq + 1) * F32_HS_STRIDE + r] = v.y;
          hs[(kq + 2) * F32_HS_STRIDE + r] = v.z;
          hs[(kq + 3) * F32_HS_STRIDE + r] = v.w;
        }
#pragma unroll
        for (int p = 0; p < 8; ++p) {
          const int ol = p * 32 + rr;
          float4 v = *(const float4*)(W1 + (long)(cbase + ol) * 1024 + kk + kq);
          float* dst = ws + (ol >> 4) * 20 + (ol & 15);
          dst[(kq + 0) * F32_WS_STRIDE] = v.x;
          dst[(kq + 1) * F32_WS_STRIDE] = v.y;
          dst[(kq + 2) * F32_WS_STRIDE] = v.z;
          dst[(kq + 3) * F32_WS_STRIDE] = v.w;
        }
      }
      __syncthreads();
#pragma unroll
      for (int k = 0; k < KT; ++k) {
        float4 a = *(const float4*)(hs + k * F32_HS_STRIDE + ty * 4);
        const float* wr = ws + k * F32_WS_STRIDE + tx * 20;
        float4 w0 = *(const float4*)(wr + 0);
        float4 w1 = *(const float4*)(wr + 4);
        float4 w2q = *(const float4*)(wr + 8);
        float4 w3 = *(const float4*)(wr + 12);
        float wv[16] = {w0.x, w0.y, w0.z, w0.w, w1.x, w1.y, w1.z, w1.w,
                        w2q.x, w2q.y, w2q.z, w2q.w, w3.x, w3.y, w3.z, w3.w};
#pragma unroll
        for (int c = 0; c < 16; ++c) {
          acc[c][0] += a.x * wv[c];
          acc[c][1] += a.y * wv[c];
          acc[c][2] += a.z * wv[c];
          acc[c][3] += a.w * wv[c];
        }
      }
    }

    __syncthreads();
#pragma unroll
    for (int c = 0; c < 16; ++c) {
      const int cloc = tx * 16 + c;
#pragma unroll
      for (int j = 0; j < 4; ++j)
        Al[cloc * A_STRIDE + ty * 4 + j] = fast_tanh(acc[c][j] + b1v[c]);
    }

    for (int c2 = 0; c2 < 256; c2 += KT) {
      __syncthreads();
      {
        const int e = t >> 2;
        const int cq = (t & 3) * 8;
#pragma unroll
        for (int p = 0; p < 2; ++p) {
          float4 v = *(const float4*)(W2 + (long)e * 1024 + cbase + c2 + cq + p * 4);
          w2s[(cq + p * 4 + 0) * W2S_STRIDE + e] = v.x;
          w2s[(cq + p * 4 + 1) * W2S_STRIDE + e] = v.y;
          w2s[(cq + p * 4 + 2) * W2S_STRIDE + e] = v.z;
          w2s[(cq + p * 4 + 3) * W2S_STRIDE + e] = v.w;
        }
      }
      __syncthreads();
#pragma unroll
      for (int c = 0; c < KT; ++c) {
        const int cloc = c2 + c;
        const float* ap = Al + cloc * A_STRIDE + tx * 4;
        const float a0 = ap[0], a1 = ap[1], a2 = ap[2], a3 = ap[3];
        const float4 wv = *(const float4*)(w2s + c * W2S_STRIDE + ty * 4);
        lacc[0][0] += a0 * wv.x; lacc[0][1] += a0 * wv.y; lacc[0][2] += a0 * wv.z; lacc[0][3] += a0 * wv.w;
        lacc[1][0] += a1 * wv.x; lacc[1][1] += a1 * wv.y; lacc[1][2] += a1 * wv.z; lacc[1][3] += a1 * wv.w;
        lacc[2][0] += a2 * wv.x; lacc[2][1] += a2 * wv.y; lacc[2][2] += a2 * wv.z; lacc[2][3] += a2 * wv.w;
        lacc[3][0] += a3 * wv.x; lacc[3][1] += a3 * wv.y; lacc[3][2] += a3 * wv.z; lacc[3][3] += a3 * wv.w;
      }
    }
  }

  __syncthreads();
#pragma unroll
  for (int j = 0; j < 4; ++j)
#pragma unroll
    for (int l = 0; l < 4; ++l)
      smem[(tx * 4 + j) * 68 + ty * 4 + l] = lacc[j][l] + b2v[l];
  __syncthreads();

  {
    const int row = t >> 2;
    const int sub = t & 3;
    float v1 = -1e30f, v2 = -1e30f;
    int i1 = -1, i2 = -1;
#pragma unroll
    for (int j = 0; j < 16; ++j) {
      const float v = smem[row * 68 + sub * 16 + j];
      const int idx = sub * 16 + j;
      if (v > v1) { v2 = v1; i2 = i1; v1 = v; i1 = idx; }
      else if (v > v2) { v2 = v; i2 = idx; }
    }
#pragma unroll
    for (int off = 1; off <= 2; off <<= 1) {
      const float ov1 = __shfl_xor(v1, off);
      const int   oi1 = __shfl_xor(i1, off);
      const float ov2 = __shfl_xor(v2, off);
      const int   oi2 = __shfl_xor(i2, off);
      if (ov1 > v1) {
        if (v1 > ov2) { v2 = v1; i2 = i1; }
        else          { v2 = ov2; i2 = oi2; }
        v1 = ov1; i1 = oi1;
      } else if (ov1 > v2) {
        v2 = ov1; i2 = oi1;
      }
    }
    const float e2 = __expf(v2 - v1);
    const float inv = 1.0f / (1.0f + e2);
    const float p1 = inv, p2 = e2 * inv;
    float* orow = out + (rowbase + row) * 64 + sub * 16;
#pragma unroll
    for (int q = 0; q < 4; ++q) {
      const int idx0 = sub * 16 + q * 4;
      float4 o;
      o.x = (idx0 + 0 == i1) ? p1 : ((idx0 + 0 == i2) ? p2 : 0.0f);
      o.y = (idx0 + 1 == i1) ? p1 : ((idx0 + 1 == i2) ? p2 : 0.0f);
      o.z = (idx0 + 2 == i1) ? p1 : ((idx0 + 2 == i2) ? p2 : 0.0f);
      o.w = (idx0 + 3 == i1) ? p1 : ((idx0 + 3 == i2) ? p2 : 0.0f);
      *(float4*)(orow + q * 4) = o;
    }
  }
}

extern "C" void kernel_launch(void* const* d_in, const int* in_sizes, int n_in,
                              void* d_out, int out_size, void* d_ws, size_t ws_size,
                              hipStream_t stream) {
  const float* h  = (const float*)d_in[0];
  const float* W1 = (const float*)d_in[1];
  const float* b1 = (const float*)d_in[2];
  const float* W2 = (const float*)d_in[3];
  const float* b2 = (const float*)d_in[4];
  float* out = (float*)d_out;
  // epoch=5 >= warmup=0 and top_k=2 -> top-2 masked softmax path (inputs fixed by harness)
  if (d_ws && ws_size >= (size_t)4 * 1024 * 1024) {
    _Float16* wsp = (_Float16*)d_ws;
    w1_split<<<dim3(512), dim3(256), 0, stream>>>(W1, wsp);
    gating_mfma3<<<dim3(131072 / 128), dim3(512), 0, stream>>>(h, wsp, b1, W2, b2, out);
  } else {
    gating_fused<<<dim3(131072 / 64), dim3(256), 0, stream>>>(h, W1, b1, W2, b2, out);
  }
}